// Round 16
// baseline (173.897 us; speedup 1.0000x reference)
//
#include <hip/hip_runtime.h>
#include <hip/hip_bf16.h>
#include <stdint.h>

typedef unsigned short ushort_t;
typedef __attribute__((ext_vector_type(8))) __bf16 bf16x8;
typedef __attribute__((ext_vector_type(4))) float f32x4;

typedef const __attribute__((address_space(1))) uint32_t* gptr_t;
typedef __attribute__((address_space(3))) uint32_t* lptr_t;

__device__ __forceinline__ ushort_t f2bf(float f) {
  union { float f; uint32_t u; } x; x.f = f;
  uint32_t u = x.u;
  uint32_t r = (u + 0x7fffu + ((u >> 16) & 1u)) >> 16;
  return (ushort_t)r;
}

__device__ __forceinline__ uint32_t cvt_pk_bf16(float lo, float hi) {
  uint32_t r;
  asm("v_cvt_pk_bf16_f32 %0, %1, %2" : "=v"(r) : "v"(lo), "v"(hi));
  return r;
}

__device__ __forceinline__ void gload_lds16(const void* g, void* l) {
  __builtin_amdgcn_global_load_lds((gptr_t)g, (lptr_t)l, 16, 0, 0);
}

// ---------------- fused prep: cast x + transpose-cast both weights ----------------
__global__ void prep(const float* __restrict__ x, ushort_t* __restrict__ xb,
                     const float* __restrict__ Wa, ushort_t* __restrict__ Wab,
                     const float* __restrict__ Wp, ushort_t* __restrict__ Wpb) {
  const int bid = blockIdx.x;
  if (bid < 8192) {
    const int idx = (bid * 256 + threadIdx.x) * 4;
    const float4 v = *(const float4*)(x + idx);
    ushort4 o;
    o.x = f2bf(v.x); o.y = f2bf(v.y); o.z = f2bf(v.z); o.w = f2bf(v.w);
    *(ushort4*)(xb + idx) = o;
  } else {
    __shared__ ushort_t t[32][33];
    const float* in; ushort_t* out; int N, n0, k0;
    const int K = 1024;
    if (bid < 11264) {
      const int i = bid - 8192; in = Wa; out = Wab; N = 3072;
      n0 = (i % 96) * 32; k0 = (i / 96) * 32;
    } else {
      const int i = bid - 11264; in = Wp; out = Wpb; N = 1024;
      n0 = (i % 32) * 32; k0 = (i / 32) * 32;
    }
    const int c = threadIdx.x & 31, r0 = threadIdx.x >> 5;
#pragma unroll
    for (int i = 0; i < 4; ++i) {
      const int r = r0 + i * 8;
      t[r][c] = f2bf(in[(size_t)(k0 + r) * N + n0 + c]);
    }
    __syncthreads();
#pragma unroll
    for (int i = 0; i < 4; ++i) {
      const int r = r0 + i * 8;
      out[(size_t)(n0 + r) * K + k0 + c] = t[c][r];
    }
  }
}

// ---------------- GEMM: C[M,N] = A[M,K] * Bt[N,K]^T + bias ----------------
// MODE 1: fp32 out to Cf.
// MODE 2: bf16 out scattered: Q,K -> [BH][S][D] (Q pre-scaled), V -> [BH][D][S].
template<int MODE>
__global__ __launch_bounds__(256, 4) void gemm_bt(
    const ushort_t* __restrict__ A, const ushort_t* __restrict__ Bt,
    const float* __restrict__ bias,
    ushort_t* __restrict__ Cq, ushort_t* __restrict__ Ck, ushort_t* __restrict__ Cv,
    float* __restrict__ Cf,
    int M, int N, int K, float qscale)
{
  __shared__ ushort_t As[128 * 64];
  __shared__ ushort_t Bs[128 * 64];
  const int tid = threadIdx.x;
  const int w = tid >> 6, l = tid & 63;
  const int bm = blockIdx.y * 128, bn = blockIdx.x * 128;
  const int lr = l >> 3, lp = l & 7;
  const int l16 = l & 15, lhi = l >> 4;
  const int wm = (w >> 1) * 64, wn = (w & 1) * 64;

  f32x4 acc[4][4] = {};

  for (int kt = 0; kt < K; kt += 64) {
#pragma unroll
    for (int i = 0; i < 4; ++i) {
      const int ci = i * 4 + w;
      const int row = ci * 8 + lr;
      const int sc = (lp ^ (row & 7)) * 8;
      gload_lds16(A + (size_t)(bm + row) * K + kt + sc, &As[ci * 512]);
      gload_lds16(Bt + (size_t)(bn + row) * K + kt + sc, &Bs[ci * 512]);
    }
    __syncthreads();

    bf16x8 af[4][2], bfr[4][2];
#pragma unroll
    for (int mf = 0; mf < 4; ++mf) {
      const int row = wm + mf * 16 + l16;
#pragma unroll
      for (int kf = 0; kf < 2; ++kf) {
        const int ch = (lhi + kf * 4) ^ (row & 7);
        af[mf][kf] = *(const bf16x8*)((const char*)&As[row * 64] + ch * 16);
      }
    }
#pragma unroll
    for (int nf = 0; nf < 4; ++nf) {
      const int row = wn + nf * 16 + l16;
#pragma unroll
      for (int kf = 0; kf < 2; ++kf) {
        const int ch = (lhi + kf * 4) ^ (row & 7);
        bfr[nf][kf] = *(const bf16x8*)((const char*)&Bs[row * 64] + ch * 16);
      }
    }
#pragma unroll
    for (int kf = 0; kf < 2; ++kf)
#pragma unroll
      for (int mf = 0; mf < 4; ++mf)
#pragma unroll
        for (int nf = 0; nf < 4; ++nf)
          acc[mf][nf] = __builtin_amdgcn_mfma_f32_16x16x32_bf16(
              af[mf][kf], bfr[nf][kf], acc[mf][nf], 0, 0, 0);
    __syncthreads();
  }

#pragma unroll
  for (int mf = 0; mf < 4; ++mf) {
#pragma unroll
    for (int nf = 0; nf < 4; ++nf) {
      const int col = bn + wn + nf * 16 + l16;
      const float bv = bias[col];
#pragma unroll
      for (int r = 0; r < 4; ++r) {
        const int row = bm + wm + mf * 16 + lhi * 4 + r;
        float v = acc[mf][nf][r] + bv;
        if constexpr (MODE == 1) {
          Cf[(size_t)row * N + col] = v;
        } else {
          const int region = col >> 10;
          const int hcol = col & 1023;
          const int b_ = row >> 10, s_ = row & 1023;
          const int h_ = hcol >> 6, d_ = hcol & 63;
          if (region == 2) {
            // V: write transposed [BH][D][S]
            Cv[((size_t)(b_ * 16 + h_) * 64 + d_) * 1024 + s_] = f2bf(v);
          } else {
            ushort_t* base = (region == 0) ? Cq : Ck;
            if (region == 0) v *= qscale;
            base[((size_t)(b_ * 16 + h_) * 1024 + s_) * 64 + d_] = f2bf(v);
          }
        }
      }
    }
  }
}

// ---------------- causal flash attention (swapped-operand, paired, LDS-staged K/V) ----------------
// Fixed-max softmax (scores pre-scaled by log2(e)/8, bounded): P = exp2(s), per-lane
// partial l, one cross-lane reduce at the end. K/V^T staged once per block into LDS
// (global_load_lds, double-buffered, XOR-swizzled), shared by all 4 waves.
// ANTI-CORRELATED PAIRING: round-robin dispatch puts bid and bid+256 on the same CU;
// with p = (bid>>3)&3 both had the SAME NT (16+16 vs 10+10 -> 23% CU tail). For
// bid>=256 we flip p -> 3-p so every CU totals 26 tile-iterations (16+10 or 14+12).
__global__ __launch_bounds__(256, 2) void attn_kernel(
    const ushort_t* __restrict__ Q, const ushort_t* __restrict__ Kk,
    const ushort_t* __restrict__ Vt, ushort_t* __restrict__ O)
{
  __shared__ ushort_t Kl[2][64 * 64];   // [buf][kv 64][ch 64], 128B rows, swizzled
  __shared__ ushort_t Vl[2][64 * 64];   // [buf][d 64][kv-ch 64]
  __shared__ ushort_t Pl[4][32 * 68];   // [wave][q 32][64 kv + 4 pad], reused by H then L
  const int tid = threadIdx.x;
  const int w = tid >> 6, l = tid & 63;
  const int l16 = l & 15, lhi = l >> 4;

  const int bid = blockIdx.x;
  const int bh = ((bid >> 5) << 3) | (bid & 7);   // head 0..127 (bid&7 = head&7 -> XCD)
  const int praw = (bid >> 3) & 3;
  const int p = (bid < 256) ? praw : 3 - praw;    // anti-correlated across CU co-residents
  const int qtH = 7 - p, qtL = p;
  const int qbH = qtH * 128 + w * 32;
  const int qbL = qtL * 128 + w * 32;
  const int ntH = (qbH >> 6) + 1;
  const int ntL = (qbL >> 6) + 1;
  const int NT  = 2 * qtH + 2;                    // block-uniform loop count (max ntH)
  const size_t hb = (size_t)bh * (1024 * 64);
  const int b_ = bh >> 4, h_ = bh & 15;

  // staging geometry: wave w covers rows [j*32 + w*8 + (l>>3)], chunk (l&7), pre-swizzled src
  const int srow = l >> 3;            // 0..7
  const int sch  = l & 7;
  const int schs = sch ^ srow;        // source chunk (involution of read swizzle)

  auto STAGE = [&](int buf, int t) {
    const int kv0 = t * 64;
#pragma unroll
    for (int j = 0; j < 2; ++j) {
      const int row = j * 32 + w * 8 + srow;
      gload_lds16(Kk + hb + (size_t)(kv0 + row) * 64 + schs * 8, &Kl[buf][row * 64 + sch * 8]);
      gload_lds16(Vt + hb + (size_t)row * 1024 + kv0 + schs * 8, &Vl[buf][row * 64 + sch * 8]);
    }
  };

  // Q fragments (B-operand: lane holds Q[q=l16][ch=kf*32+lhi*8+j])
  bf16x8 qfH[2][2], qfL[2][2];
#pragma unroll
  for (int mf = 0; mf < 2; ++mf)
#pragma unroll
    for (int kf = 0; kf < 2; ++kf) {
      qfH[mf][kf] = *(const bf16x8*)(Q + hb + (size_t)(qbH + mf * 16 + l16) * 64 + kf * 32 + lhi * 8);
      qfL[mf][kf] = *(const bf16x8*)(Q + hb + (size_t)(qbL + mf * 16 + l16) * 64 + kf * 32 + lhi * 8);
    }

  f32x4 oH[2][4] = {}, oL[2][4] = {};
  float lsH[2] = {0.0f, 0.0f};
  float lsL[2] = {0.0f, 0.0f};
  char* const pbase = (char*)&Pl[w][0];

  STAGE(0, 0);
  __syncthreads();

  for (int t = 0; t < NT; ++t) {
    const int buf = t & 1;
    if (t + 1 < NT) STAGE(buf ^ 1, t + 1);   // in flight under this tile's compute
    const int kv0 = t * 64;

    auto half = [&](const bf16x8 (&qf)[2][2], f32x4 (&o)[2][4], float (&l_run)[2],
                    const int qbase) {
      // S^T[kv][q] = K·Q^T ; K fragments from swizzled LDS
      f32x4 s[2][4] = {};
#pragma unroll
      for (int nf = 0; nf < 4; ++nf) {
        const int row = nf * 16 + l16;
#pragma unroll
        for (int kf = 0; kf < 2; ++kf) {
          const int bo = (kf * 64 + lhi * 16) ^ ((row & 7) << 4);
          const bf16x8 kb = *(const bf16x8*)((const char*)&Kl[buf][row * 64] + bo);
#pragma unroll
          for (int mf = 0; mf < 2; ++mf)
            s[mf][nf] = __builtin_amdgcn_mfma_f32_16x16x32_bf16(kb, qf[mf][kf], s[mf][nf], 0, 0, 0);
        }
      }

      if (kv0 + 63 > qbase) {  // diagonal tile: elementwise causal mask
#pragma unroll
        for (int mf = 0; mf < 2; ++mf) {
          const int q = qbase + mf * 16 + l16;
#pragma unroll
          for (int nf = 0; nf < 4; ++nf)
#pragma unroll
            for (int r = 0; r < 4; ++r) {
              const int kv = kv0 + nf * 16 + lhi * 4 + r;
              if (kv > q) s[mf][nf][r] = -1e30f;
            }
        }
      }

      // P = exp2(s); per-lane partial l; P -> LDS (bf16)
#pragma unroll
      for (int mf = 0; mf < 2; ++mf) {
        float psum = 0.0f;
#pragma unroll
        for (int nf = 0; nf < 4; ++nf)
#pragma unroll
          for (int r = 0; r < 4; ++r) {
            const float pv = exp2f(s[mf][nf][r]);
            s[mf][nf][r] = pv;
            psum += pv;
          }
        l_run[mf] += psum;

        const int q = mf * 16 + l16;
#pragma unroll
        for (int nf = 0; nf < 4; ++nf) {
          const uint32_t u0 = cvt_pk_bf16(s[mf][nf][0], s[mf][nf][1]);
          const uint32_t u1 = cvt_pk_bf16(s[mf][nf][2], s[mf][nf][3]);
          *(uint2*)(pbase + q * 136 + nf * 32 + lhi * 8) = make_uint2(u0, u1);
        }
      }

      // O^T += V^T·P^T ; V fragments from swizzled LDS
#pragma unroll
      for (int kf = 0; kf < 2; ++kf) {
        bf16x8 vbf[4];
#pragma unroll
        for (int nf = 0; nf < 4; ++nf) {
          const int row = nf * 16 + l16;
          const int bo = (kf * 64 + lhi * 16) ^ ((row & 7) << 4);
          vbf[nf] = *(const bf16x8*)((const char*)&Vl[buf][row * 64] + bo);
        }
#pragma unroll
        for (int mf = 0; mf < 2; ++mf) {
          const int q = mf * 16 + l16;
          const bf16x8 pb8 = *(const bf16x8*)(pbase + q * 136 + kf * 64 + lhi * 16);
#pragma unroll
          for (int nf = 0; nf < 4; ++nf)
            o[mf][nf] = __builtin_amdgcn_mfma_f32_16x16x32_bf16(vbf[nf], pb8, o[mf][nf], 0, 0, 0);
        }
      }
    };

    if (t < ntH) half(qfH, oH, lsH, qbH);
    if (t < ntL) half(qfL, oL, lsL, qbL);

    __syncthreads();   // all waves done reading buf; stage(t+1) landed
  }

  // epilogue: cross-lane l reduce (once), normalize, pack 4 bf16 per store
  auto epi = [&](f32x4 (&o)[2][4], float (&l_run)[2], const int qbase) {
#pragma unroll
    for (int mf = 0; mf < 2; ++mf) {
      float lt = l_run[mf];
      lt += __shfl_xor(lt, 16);
      lt += __shfl_xor(lt, 32);
      const float inv = 1.0f / lt;
      const int qrow = qbase + mf * 16 + l16;
      const size_t rb = ((size_t)(b_ * 1024 + qrow)) * 1024 + h_ * 64;
#pragma unroll
      for (int nf = 0; nf < 4; ++nf) {
        const uint32_t u0 = cvt_pk_bf16(o[mf][nf][0] * inv, o[mf][nf][1] * inv);
        const uint32_t u1 = cvt_pk_bf16(o[mf][nf][2] * inv, o[mf][nf][3] * inv);
        *(uint2*)(O + rb + nf * 16 + lhi * 4) = make_uint2(u0, u1);
      }
    }
  };
  epi(oH, lsH, qbH);
  epi(oL, lsL, qbL);
}

extern "C" void kernel_launch(void* const* d_in, const int* in_sizes, int n_in,
                              void* d_out, int out_size, void* d_ws, size_t ws_size,
                              hipStream_t stream) {
  const float* x      = (const float*)d_in[0];
  const float* W_attn = (const float*)d_in[1];
  const float* b_attn = (const float*)d_in[2];
  const float* W_proj = (const float*)d_in[3];
  const float* b_proj = (const float*)d_in[4];
  float* out = (float*)d_out;

  const int M = 8192;       // B*S
  const int E = 1024, N3 = 3072;
  const size_t T = (size_t)M * E;

  char* p = (char*)d_ws;
  ushort_t* xb  = (ushort_t*)p; p += T * 2;              // x bf16; reused as attn_out
  ushort_t* Wab = (ushort_t*)p; p += (size_t)N3 * E * 2; // W_attn^T bf16 [3072][1024]
  ushort_t* Wpb = (ushort_t*)p; p += (size_t)E * E * 2;  // W_proj^T bf16 [1024][1024]
  ushort_t* Qb  = (ushort_t*)p; p += T * 2;              // [BH][S][D]
  ushort_t* Kb  = (ushort_t*)p; p += T * 2;              // [BH][S][D]
  ushort_t* Vtb = (ushort_t*)p; p += T * 2;              // [BH][D][S]

  const float qscale = 0.125f * 1.4426950408889634f;     // 1/sqrt(D) * log2(e)

  prep<<<dim3(12288), dim3(256), 0, stream>>>(x, xb, W_attn, Wab, W_proj, Wpb);
  gemm_bt<2><<<dim3(N3 / 128, M / 128), dim3(256), 0, stream>>>(
      xb, Wab, b_attn, Qb, Kb, Vtb, nullptr, M, N3, E, qscale);
  attn_kernel<<<dim3(512), dim3(256), 0, stream>>>(Qb, Kb, Vtb, xb);
  gemm_bt<1><<<dim3(E / 128, M / 128), dim3(256), 0, stream>>>(
      xb, Wpb, b_proj, nullptr, nullptr, nullptr, out, M, E, E, 1.0f);
}

// Round 17
// 171.437 us; speedup vs baseline: 1.0143x; 1.0143x over previous
//
#include <hip/hip_runtime.h>
#include <hip/hip_bf16.h>
#include <stdint.h>

typedef unsigned short ushort_t;
typedef __attribute__((ext_vector_type(8))) __bf16 bf16x8;
typedef __attribute__((ext_vector_type(4))) float f32x4;

typedef const __attribute__((address_space(1))) uint32_t* gptr_t;
typedef __attribute__((address_space(3))) uint32_t* lptr_t;

__device__ __forceinline__ ushort_t f2bf(float f) {
  union { float f; uint32_t u; } x; x.f = f;
  uint32_t u = x.u;
  uint32_t r = (u + 0x7fffu + ((u >> 16) & 1u)) >> 16;
  return (ushort_t)r;
}

__device__ __forceinline__ uint32_t cvt_pk_bf16(float lo, float hi) {
  uint32_t r;
  asm("v_cvt_pk_bf16_f32 %0, %1, %2" : "=v"(r) : "v"(lo), "v"(hi));
  return r;
}

__device__ __forceinline__ void gload_lds16(const void* g, void* l) {
  __builtin_amdgcn_global_load_lds((gptr_t)g, (lptr_t)l, 16, 0, 0);
}

// ---------------- fused prep: cast x + transpose-cast both weights ----------------
__global__ void prep(const float* __restrict__ x, ushort_t* __restrict__ xb,
                     const float* __restrict__ Wa, ushort_t* __restrict__ Wab,
                     const float* __restrict__ Wp, ushort_t* __restrict__ Wpb) {
  const int bid = blockIdx.x;
  if (bid < 8192) {
    const int idx = (bid * 256 + threadIdx.x) * 4;
    const float4 v = *(const float4*)(x + idx);
    ushort4 o;
    o.x = f2bf(v.x); o.y = f2bf(v.y); o.z = f2bf(v.z); o.w = f2bf(v.w);
    *(ushort4*)(xb + idx) = o;
  } else {
    __shared__ ushort_t t[32][33];
    const float* in; ushort_t* out; int N, n0, k0;
    const int K = 1024;
    if (bid < 11264) {
      const int i = bid - 8192; in = Wa; out = Wab; N = 3072;
      n0 = (i % 96) * 32; k0 = (i / 96) * 32;
    } else {
      const int i = bid - 11264; in = Wp; out = Wpb; N = 1024;
      n0 = (i % 32) * 32; k0 = (i / 32) * 32;
    }
    const int c = threadIdx.x & 31, r0 = threadIdx.x >> 5;
#pragma unroll
    for (int i = 0; i < 4; ++i) {
      const int r = r0 + i * 8;
      t[r][c] = f2bf(in[(size_t)(k0 + r) * N + n0 + c]);
    }
    __syncthreads();
#pragma unroll
    for (int i = 0; i < 4; ++i) {
      const int r = r0 + i * 8;
      out[(size_t)(n0 + r) * K + k0 + c] = t[c][r];
    }
  }
}

// ---------------- GEMM: C[M,N] = A[M,K] * Bt[N,K]^T + bias ----------------
// MODE 1: fp32 out to Cf.
// MODE 2: bf16 out scattered: Q,K -> [BH][S][D] (Q pre-scaled), V -> [BH][D][S].
template<int MODE>
__global__ __launch_bounds__(256, 4) void gemm_bt(
    const ushort_t* __restrict__ A, const ushort_t* __restrict__ Bt,
    const float* __restrict__ bias,
    ushort_t* __restrict__ Cq, ushort_t* __restrict__ Ck, ushort_t* __restrict__ Cv,
    float* __restrict__ Cf,
    int M, int N, int K, float qscale)
{
  __shared__ ushort_t As[128 * 64];
  __shared__ ushort_t Bs[128 * 64];
  const int tid = threadIdx.x;
  const int w = tid >> 6, l = tid & 63;
  const int bm = blockIdx.y * 128, bn = blockIdx.x * 128;
  const int lr = l >> 3, lp = l & 7;
  const int l16 = l & 15, lhi = l >> 4;
  const int wm = (w >> 1) * 64, wn = (w & 1) * 64;

  f32x4 acc[4][4] = {};

  for (int kt = 0; kt < K; kt += 64) {
#pragma unroll
    for (int i = 0; i < 4; ++i) {
      const int ci = i * 4 + w;
      const int row = ci * 8 + lr;
      const int sc = (lp ^ (row & 7)) * 8;
      gload_lds16(A + (size_t)(bm + row) * K + kt + sc, &As[ci * 512]);
      gload_lds16(Bt + (size_t)(bn + row) * K + kt + sc, &Bs[ci * 512]);
    }
    __syncthreads();

    bf16x8 af[4][2], bfr[4][2];
#pragma unroll
    for (int mf = 0; mf < 4; ++mf) {
      const int row = wm + mf * 16 + l16;
#pragma unroll
      for (int kf = 0; kf < 2; ++kf) {
        const int ch = (lhi + kf * 4) ^ (row & 7);
        af[mf][kf] = *(const bf16x8*)((const char*)&As[row * 64] + ch * 16);
      }
    }
#pragma unroll
    for (int nf = 0; nf < 4; ++nf) {
      const int row = wn + nf * 16 + l16;
#pragma unroll
      for (int kf = 0; kf < 2; ++kf) {
        const int ch = (lhi + kf * 4) ^ (row & 7);
        bfr[nf][kf] = *(const bf16x8*)((const char*)&Bs[row * 64] + ch * 16);
      }
    }
#pragma unroll
    for (int kf = 0; kf < 2; ++kf)
#pragma unroll
      for (int mf = 0; mf < 4; ++mf)
#pragma unroll
        for (int nf = 0; nf < 4; ++nf)
          acc[mf][nf] = __builtin_amdgcn_mfma_f32_16x16x32_bf16(
              af[mf][kf], bfr[nf][kf], acc[mf][nf], 0, 0, 0);
    __syncthreads();
  }

#pragma unroll
  for (int mf = 0; mf < 4; ++mf) {
#pragma unroll
    for (int nf = 0; nf < 4; ++nf) {
      const int col = bn + wn + nf * 16 + l16;
      const float bv = bias[col];
#pragma unroll
      for (int r = 0; r < 4; ++r) {
        const int row = bm + wm + mf * 16 + lhi * 4 + r;
        float v = acc[mf][nf][r] + bv;
        if constexpr (MODE == 1) {
          Cf[(size_t)row * N + col] = v;
        } else {
          const int region = col >> 10;
          const int hcol = col & 1023;
          const int b_ = row >> 10, s_ = row & 1023;
          const int h_ = hcol >> 6, d_ = hcol & 63;
          if (region == 2) {
            // V: write transposed [BH][D][S]
            Cv[((size_t)(b_ * 16 + h_) * 64 + d_) * 1024 + s_] = f2bf(v);
          } else {
            ushort_t* base = (region == 0) ? Cq : Ck;
            if (region == 0) v *= qscale;
            base[((size_t)(b_ * 16 + h_) * 1024 + s_) * 64 + d_] = f2bf(v);
          }
        }
      }
    }
  }
}

// ---------------- causal flash attention (paired, 16 q-rows/wave, LDS-staged K/V) ----------------
// Fixed-max softmax (scores pre-scaled by log2(e)/8, bounded): P = exp2(s), per-lane
// partial l, one cross-lane reduce at the end. 1024 blocks = 128 heads x {pair p, half
// hsel}; each wave owns 16 heavy rows + 16 light rows (uniform 16/18 halves per wave,
// two independent streams of ILP). K/V^T staged once per block (full 64-row tile) into
// double-buffered XOR-swizzled LDS -> 16-row waves do NOT re-fetch K/V (r13's failure).
// LDS 40.6 KB -> 3 blocks/CU capacity; grid 1024 -> ~12 waves/CU (was 8).
__global__ __launch_bounds__(256, 2) void attn_kernel(
    const ushort_t* __restrict__ Q, const ushort_t* __restrict__ Kk,
    const ushort_t* __restrict__ Vt, ushort_t* __restrict__ O)
{
  __shared__ ushort_t Kl[2][64 * 64];   // [buf][kv 64][ch 64], 128B rows, swizzled
  __shared__ ushort_t Vl[2][64 * 64];   // [buf][d 64][kv-ch 64]
  __shared__ ushort_t Pl[4][16 * 68];   // [wave][q 16][64 kv + 4 pad], reused by H then L
  const int tid = threadIdx.x;
  const int w = tid >> 6, l = tid & 63;
  const int l16 = l & 15, lhi = l >> 4;

  const int bid = blockIdx.x;
  const int bh = ((bid >> 6) << 3) | (bid & 7);   // head 0..127 (bid&7 = head&7 -> XCD)
  const int j  = (bid >> 3) & 7;
  const int p = j & 3, hsel = j >> 2;             // pair 0..3, 64-row half 0..1
  const int qbH = (7 - p) * 128 + hsel * 64 + w * 16;
  const int qbL = p * 128 + hsel * 64 + w * 16;
  const int ntH = 2 * (7 - p) + hsel + 1;         // block-uniform (w*16 < 64)
  const int ntL = 2 * p + hsel + 1;
  const size_t hb = (size_t)bh * (1024 * 64);
  const int b_ = bh >> 4, h_ = bh & 15;

  // staging geometry: wave w covers rows [j*32 + w*8 + (l>>3)], chunk (l&7), pre-swizzled src
  const int srow = l >> 3;            // 0..7
  const int sch  = l & 7;
  const int schs = sch ^ srow;        // source chunk (involution of read swizzle)

  auto STAGE = [&](int buf, int t) {
    const int kv0 = t * 64;
#pragma unroll
    for (int jj = 0; jj < 2; ++jj) {
      const int row = jj * 32 + w * 8 + srow;
      gload_lds16(Kk + hb + (size_t)(kv0 + row) * 64 + schs * 8, &Kl[buf][row * 64 + sch * 8]);
      gload_lds16(Vt + hb + (size_t)row * 1024 + kv0 + schs * 8, &Vl[buf][row * 64 + sch * 8]);
    }
  };

  // Q fragments (B-operand: lane holds Q[q=l16][ch=kf*32+lhi*8+j])
  bf16x8 qfH[2], qfL[2];
#pragma unroll
  for (int kf = 0; kf < 2; ++kf) {
    qfH[kf] = *(const bf16x8*)(Q + hb + (size_t)(qbH + l16) * 64 + kf * 32 + lhi * 8);
    qfL[kf] = *(const bf16x8*)(Q + hb + (size_t)(qbL + l16) * 64 + kf * 32 + lhi * 8);
  }

  f32x4 oH[4] = {}, oL[4] = {};
  float lsH = 0.0f, lsL = 0.0f;
  char* const pbase = (char*)&Pl[w][0];

  STAGE(0, 0);
  __syncthreads();

  for (int t = 0; t < ntH; ++t) {
    const int buf = t & 1;
    if (t + 1 < ntH) STAGE(buf ^ 1, t + 1);   // in flight under this tile's compute
    const int kv0 = t * 64;

    auto half = [&](const bf16x8 (&qf)[2], f32x4 (&o)[4], float& l_run,
                    const int qbase) {
      // S^T[kv][q] = K·Q^T ; K fragments from swizzled LDS
      f32x4 s[4] = {};
#pragma unroll
      for (int nf = 0; nf < 4; ++nf) {
        const int row = nf * 16 + l16;
#pragma unroll
        for (int kf = 0; kf < 2; ++kf) {
          const int bo = (kf * 64 + lhi * 16) ^ ((row & 7) << 4);
          const bf16x8 kb = *(const bf16x8*)((const char*)&Kl[buf][row * 64] + bo);
          s[nf] = __builtin_amdgcn_mfma_f32_16x16x32_bf16(kb, qf[kf], s[nf], 0, 0, 0);
        }
      }

      if (kv0 + 63 > qbase) {  // diagonal tile: elementwise causal mask
        const int q = qbase + l16;
#pragma unroll
        for (int nf = 0; nf < 4; ++nf)
#pragma unroll
          for (int r = 0; r < 4; ++r) {
            const int kv = kv0 + nf * 16 + lhi * 4 + r;
            if (kv > q) s[nf][r] = -1e30f;
          }
      }

      // P = exp2(s); per-lane partial l; P -> LDS (bf16)
      float psum = 0.0f;
#pragma unroll
      for (int nf = 0; nf < 4; ++nf)
#pragma unroll
        for (int r = 0; r < 4; ++r) {
          const float pv = exp2f(s[nf][r]);
          s[nf][r] = pv;
          psum += pv;
        }
      l_run += psum;

#pragma unroll
      for (int nf = 0; nf < 4; ++nf) {
        const uint32_t u0 = cvt_pk_bf16(s[nf][0], s[nf][1]);
        const uint32_t u1 = cvt_pk_bf16(s[nf][2], s[nf][3]);
        *(uint2*)(pbase + l16 * 136 + nf * 32 + lhi * 8) = make_uint2(u0, u1);
      }

      // O^T += V^T·P^T ; V fragments from swizzled LDS
#pragma unroll
      for (int kf = 0; kf < 2; ++kf) {
        const bf16x8 pb8 = *(const bf16x8*)(pbase + l16 * 136 + kf * 64 + lhi * 16);
#pragma unroll
        for (int nf = 0; nf < 4; ++nf) {
          const int row = nf * 16 + l16;
          const int bo = (kf * 64 + lhi * 16) ^ ((row & 7) << 4);
          const bf16x8 vbf = *(const bf16x8*)((const char*)&Vl[buf][row * 64] + bo);
          o[nf] = __builtin_amdgcn_mfma_f32_16x16x32_bf16(vbf, pb8, o[nf], 0, 0, 0);
        }
      }
    };

    half(qfH, oH, lsH, qbH);
    if (t < ntL) half(qfL, oL, lsL, qbL);

    __syncthreads();   // all waves done reading buf; stage(t+1) landed
  }

  // epilogue: cross-lane l reduce (once), normalize, pack 4 bf16 per store
  auto epi = [&](f32x4 (&o)[4], float ls, const int qbase) {
    float lt = ls;
    lt += __shfl_xor(lt, 16);
    lt += __shfl_xor(lt, 32);
    const float inv = 1.0f / lt;
    const int qrow = qbase + l16;
    const size_t rb = ((size_t)(b_ * 1024 + qrow)) * 1024 + h_ * 64;
#pragma unroll
    for (int nf = 0; nf < 4; ++nf) {
      const uint32_t u0 = cvt_pk_bf16(o[nf][0] * inv, o[nf][1] * inv);
      const uint32_t u1 = cvt_pk_bf16(o[nf][2] * inv, o[nf][3] * inv);
      *(uint2*)(O + rb + nf * 16 + lhi * 4) = make_uint2(u0, u1);
    }
  };
  epi(oH, lsH, qbH);
  epi(oL, lsL, qbL);
}

extern "C" void kernel_launch(void* const* d_in, const int* in_sizes, int n_in,
                              void* d_out, int out_size, void* d_ws, size_t ws_size,
                              hipStream_t stream) {
  const float* x      = (const float*)d_in[0];
  const float* W_attn = (const float*)d_in[1];
  const float* b_attn = (const float*)d_in[2];
  const float* W_proj = (const float*)d_in[3];
  const float* b_proj = (const float*)d_in[4];
  float* out = (float*)d_out;

  const int M = 8192;       // B*S
  const int E = 1024, N3 = 3072;
  const size_t T = (size_t)M * E;

  char* p = (char*)d_ws;
  ushort_t* xb  = (ushort_t*)p; p += T * 2;              // x bf16; reused as attn_out
  ushort_t* Wab = (ushort_t*)p; p += (size_t)N3 * E * 2; // W_attn^T bf16 [3072][1024]
  ushort_t* Wpb = (ushort_t*)p; p += (size_t)E * E * 2;  // W_proj^T bf16 [1024][1024]
  ushort_t* Qb  = (ushort_t*)p; p += T * 2;              // [BH][S][D]
  ushort_t* Kb  = (ushort_t*)p; p += T * 2;              // [BH][S][D]
  ushort_t* Vtb = (ushort_t*)p; p += T * 2;              // [BH][D][S]

  const float qscale = 0.125f * 1.4426950408889634f;     // 1/sqrt(D) * log2(e)

  prep<<<dim3(12288), dim3(256), 0, stream>>>(x, xb, W_attn, Wab, W_proj, Wpb);
  gemm_bt<2><<<dim3(N3 / 128, M / 128), dim3(256), 0, stream>>>(
      xb, Wab, b_attn, Qb, Kb, Vtb, nullptr, M, N3, E, qscale);
  attn_kernel<<<dim3(1024), dim3(256), 0, stream>>>(Qb, Kb, Vtb, xb);
  gemm_bt<1><<<dim3(E / 128, M / 128), dim3(256), 0, stream>>>(
      xb, Wpb, b_proj, nullptr, nullptr, nullptr, out, M, E, E, 1.0f);
}